// Round 9
// baseline (135.434 us; speedup 1.0000x reference)
//
#include <hip/hip_runtime.h>
#include <stdint.h>

typedef __attribute__((ext_vector_type(8))) short short8;
typedef __attribute__((ext_vector_type(4))) float f32x4;

#define NH 12
#define DH 64

// 2 x f32 -> packed 2 x bf16 (RNE) in one instruction
__device__ __forceinline__ uint32_t cvtpk(float lo, float hi) {
  uint32_t r;
  asm("v_cvt_pk_bf16_f32 %0, %1, %2" : "=v"(r) : "v"(lo), "v"(hi));
  return r;
}

typedef const __attribute__((address_space(1))) uint32_t gu32;
typedef __attribute__((address_space(3))) uint32_t lu32;

__device__ __forceinline__ void gll16(const void* src, void* lds) {
  __builtin_amdgcn_global_load_lds((gu32*)(uintptr_t)src, (lu32*)(uintptr_t)lds, 16, 0, 0);
}

// Per-head base offset in u32 units inside Kb / Vt workspace arrays.
// heads 0-3: r=1 Sd=8192; 4-7: r=2 Sd=4096; 8-11: r=4 Sd=2048; 32 u32/row.
__device__ __forceinline__ int head_base2(int h) {
  return (h < 4) ? (h << 18)
       : (h < 8) ? ((1 << 20) + ((h - 4) << 17))
                 : ((1 << 20) + (1 << 19) + ((h - 8) << 16));
}

// ---------------- prepass K: fp32 -> bf16, dilated-gathered [h][i][d] -------
__global__ __launch_bounds__(256)
void prep_k(const float* __restrict__ K, uint32_t* __restrict__ Kb) {
  const int p = blockIdx.x * 256 + threadIdx.x;   // exactly 1,835,008 pairs
  int h, r, off, sh, rem;
  if (p < 1048576)      { h = p >> 18;                    rem = p & 262143; r = 1; off = 0; sh = 9; }
  else if (p < 1572864) { int q = p - 1048576; h = 4 + (q >> 17); rem = q & 131071; r = 2; off = 1; sh = 8; }
  else                  { int q = p - 1572864; h = 8 + (q >> 16); rem = q & 65535;  r = 4; off = 2; sh = 7; }
  const int i = rem >> 5, d2 = rem & 31;
  const int j = i & ((1 << sh) - 1), b = i >> sh;
  const int tok = b * 512 + off + r * j;
  const float2 f = *reinterpret_cast<const float2*>(K + ((size_t)tok * NH + h) * DH + d2 * 2);
  Kb[p] = cvtpk(f.x, f.y);
}

// ------------- prepass V: fp32 -> bf16, transposed [h][b][d=64][jj] ---------
__global__ __launch_bounds__(256)
void prep_v(const float* __restrict__ V, short* __restrict__ Vt) {
  __shared__ short T[64][72];   // pad 72 shorts: 144B rows keep 16B alignment
  const int bid = blockIdx.x, tid = threadIdx.x;
  int h, r, off, SDB, b, tile;
  if (bid < 512)      { h = bid >> 7;            int rem = bid & 127; b = rem >> 3; tile = rem & 7; r = 1; off = 0; SDB = 512; }
  else if (bid < 768) { int t2 = bid - 512; h = 4 + (t2 >> 6); int rem = t2 & 63; b = rem >> 2; tile = rem & 3; r = 2; off = 1; SDB = 256; }
  else                { int t3 = bid - 768; h = 8 + (t3 >> 5); int rem = t3 & 31; b = rem >> 1; tile = rem & 1; r = 4; off = 2; SDB = 128; }
  const int jj0 = tile * 64;
  const int dl = (tid & 15) * 4, tl0 = tid >> 4;
  #pragma unroll
  for (int rep = 0; rep < 4; ++rep) {
    const int tokl = rep * 16 + tl0;
    const int tok = b * 512 + off + r * (jj0 + tokl);
    const float4 f = *reinterpret_cast<const float4*>(V + ((size_t)tok * NH + h) * DH + dl);
    const uint32_t u01 = cvtpk(f.x, f.y), u23 = cvtpk(f.z, f.w);
    T[dl + 0][tokl] = (short)(u01 & 0xffffu);
    T[dl + 1][tokl] = (short)(u01 >> 16);
    T[dl + 2][tokl] = (short)(u23 & 0xffffu);
    T[dl + 3][tokl] = (short)(u23 >> 16);
  }
  __syncthreads();
  const size_t hbase = (size_t)head_base2(h) * 2;
  #pragma unroll
  for (int cc = 0; cc < 2; ++cc) {
    const int c = tid * 2 + cc, d = c >> 3, s = c & 7;
    short8 v = *reinterpret_cast<const short8*>(&T[d][s * 8]);
    *reinterpret_cast<short8*>(Vt + hbase + (size_t)(b * 64 + d) * SDB + jj0 + s * 8) = v;
  }
}

// ------------------------------ main kernel --------------------------------
// 4-wave block = 64 dilated q-rows of one (rb, h). K/V tiles span the full
// segment (TROWS); staged via global_load_lds from the bf16 prepass arrays
// with pre-swizzled source addresses (linear LDS dest). PV accumulates across
// the <=5 col blocks in registers -> one plain store per output element.
template<int M, int R>
__device__ __forceinline__ void unit(
    const float* __restrict__ Q, float* __restrict__ Out,
    const char* __restrict__ KbB, const char* __restrict__ VtB,
    int rb, int h, int j0, char* lds)
{
  constexpr int OFF    = (R == 1) ? 0 : ((R == 2) ? 1 : 2);
  constexpr int SDB    = 512 / R;
  constexpr int TROWS  = (M == 128) ? 128 : 64;  // K rows / V cols in tile
  constexpr int NT     = M / 16;
  constexpr int HALVES = (M == 128) ? 2 : 1;
  constexpr int TTP    = NT / HALVES;            // tt per half
  constexpr int KKP    = (M == 128) ? 2 : 1;     // PV k-steps per half
  constexpr int PROW   = (M == 128) ? 64 : 32;   // shorts per P row
  constexpr int PMASK  = (M == 128) ? 7 : 3;
  constexpr int VMASK  = (TROWS / 8) - 1;        // 15 or 7
  constexpr int VROWB  = TROWS * 2;              // bytes per V^T row
  constexpr int NSEG   = TROWS / 8;              // 16 or 8 (1KB segs per tile)

  const char* kbh = KbB + (size_t)head_base2(h) * 4;
  const char* vth = VtB + (size_t)head_base2(h) * 4;

  const int tid = threadIdx.x, w = tid >> 6, lane = tid & 63;
  const int lhi = lane >> 4, llo = lane & 15;
  const int jc0  = (M == 128) ? (j0 & ~127) : j0;   // tile/segment col base
  const int c_lo = (M == 128) ? 0 : ((w >> 1) * 32);
  char* Klds = lds;
  char* Vlds = lds + 16384;
  short* const P = (short*)(lds + 32768 + w * 2048);

  // Q fragments, scale log2(e)/8 folded in
  short8 qf0, qf1;
  {
    const float SCL = 0.18033688f;
    const int tok = rb * 512 + OFF + R * (j0 + w * 16 + llo);
    const float* src = Q + ((size_t)tok * NH + h) * DH + lhi * 8;
    float4 a0 = *reinterpret_cast<const float4*>(src);
    float4 a1 = *reinterpret_cast<const float4*>(src + 4);
    float4 b0 = *reinterpret_cast<const float4*>(src + 32);
    float4 b1 = *reinterpret_cast<const float4*>(src + 36);
    union { uint32_t u[4]; short8 s; } x0, x1;
    x0.u[0] = cvtpk(a0.x * SCL, a0.y * SCL); x0.u[1] = cvtpk(a0.z * SCL, a0.w * SCL);
    x0.u[2] = cvtpk(a1.x * SCL, a1.y * SCL); x0.u[3] = cvtpk(a1.z * SCL, a1.w * SCL);
    x1.u[0] = cvtpk(b0.x * SCL, b0.y * SCL); x1.u[1] = cvtpk(b0.z * SCL, b0.w * SCL);
    x1.u[2] = cvtpk(b1.x * SCL, b1.y * SCL); x1.u[3] = cvtpk(b1.z * SCL, b1.w * SCL);
    qf0 = x0.s; qf1 = x1.s;
  }

  f32x4 acc[4];
  #pragma unroll
  for (int dt = 0; dt < 4; ++dt) acc[dt] = f32x4{0.f, 0.f, 0.f, 0.f};

  const int c0 = (rb - 2 < 0) ? 0 : rb - 2;
  const int c1 = (rb + 2 > 15) ? 15 : rb + 2;

  for (int cb = c0; cb <= c1; ++cb) {
    __syncthreads();   // prev iteration's LDS readers done
    // ---- stage K tile: linear LDS dest, inverse-swizzled global src ----
    #pragma unroll
    for (int n = 0; n < NSEG / 4; ++n) {
      const int seg = n * 4 + w;
      const int ck = seg * 64 + lane, t = ck >> 3, sp = ck & 7;
      gll16(kbh + (size_t)(cb * SDB + jc0 + t) * 128 + ((sp ^ (t & 7)) << 4),
            Klds + seg * 1024);
    }
    // ---- stage V^T tile ----
    #pragma unroll
    for (int n = 0; n < NSEG / 4; ++n) {
      const int seg = n * 4 + w;
      const int ck = seg * 64 + lane;
      const int d = ck / (TROWS / 8), sp = ck & VMASK;
      gll16(vth + ((size_t)(cb * 64 + d) * SDB + jc0 + ((sp ^ (d & VMASK)) << 3)) * 2,
            Vlds + seg * 1024);
    }
    __syncthreads();   // drains vmcnt: staged tiles visible

    // ---- QK^T ----
    f32x4 sc[NT];
    #pragma unroll
    for (int tt = 0; tt < NT; ++tt) sc[tt] = f32x4{0.f, 0.f, 0.f, 0.f};
    #pragma unroll
    for (int kk = 0; kk < 2; ++kk) {
      #pragma unroll
      for (int tt = 0; tt < NT; ++tt) {
        const int t = c_lo + tt * 16 + llo;
        const int slot = (4 * kk + lhi) ^ (t & 7);
        short8 kf = *reinterpret_cast<const short8*>(Klds + t * 128 + slot * 16);
        sc[tt] = __builtin_amdgcn_mfma_f32_16x16x32_bf16(kk ? qf1 : qf0, kf, sc[tt], 0, 0, 0);
      }
    }
    // ---- softmax (no max pass: scores bounded, shift-invariant) ----
    float sm[4] = {0.f, 0.f, 0.f, 0.f};
    #pragma unroll
    for (int tt = 0; tt < NT; ++tt)
      #pragma unroll
      for (int i = 0; i < 4; ++i) {
        const float p = exp2f(sc[tt][i]);
        sc[tt][i] = p;
        sm[i] += p;
      }
    #pragma unroll
    for (int i = 0; i < 4; ++i) {
      sm[i] += __shfl_xor(sm[i], 1);
      sm[i] += __shfl_xor(sm[i], 2);
      sm[i] += __shfl_xor(sm[i], 4);
      sm[i] += __shfl_xor(sm[i], 8);
      sm[i] = 1.0f / sm[i];
    }
    // ---- per-half: P -> LDS (2KB/wave buffer), then PV ----
    #pragma unroll
    for (int h2 = 0; h2 < HALVES; ++h2) {
      #pragma unroll
      for (int ttl = 0; ttl < TTP; ++ttl) {
        const int tt = h2 * TTP + ttl;
        #pragma unroll
        for (int ip = 0; ip < 2; ++ip) {
          const uint32_t pk = cvtpk(sc[tt][2 * ip] * sm[2 * ip],
                                    sc[tt][2 * ip + 1] * sm[2 * ip + 1]);
          const int q0 = 4 * lhi + 2 * ip;
          const int chunk = 2 * ttl + (llo >> 3);
          P[q0 * PROW + ((chunk ^ (q0 & PMASK)) << 3) + (llo & 7)] = (short)(pk & 0xffffu);
          P[(q0 + 1) * PROW + ((chunk ^ ((q0 + 1) & PMASK)) << 3) + (llo & 7)] = (short)(pk >> 16);
        }
      }
      #pragma unroll
      for (int kkl = 0; kkl < KKP; ++kkl) {
        const int pch = (KKP == 2) ? (4 * kkl + lhi) : lhi;
        short8 pf = *reinterpret_cast<const short8*>(
            (const short*)P + llo * PROW + ((pch ^ (llo & PMASK)) << 3));
        #pragma unroll
        for (int dt = 0; dt < 4; ++dt) {
          const int d = dt * 16 + llo;
          const int lc = (M == 128) ? (8 * h2 + 4 * kkl + lhi) : (c_lo / 8 + lhi);
          short8 vf = *reinterpret_cast<const short8*>(
              Vlds + d * VROWB + ((lc ^ (d & VMASK)) << 4));
          acc[dt] = __builtin_amdgcn_mfma_f32_16x16x32_bf16(pf, vf, acc[dt], 0, 0, 0);
        }
      }
    }
  }

  // ---- epilogue: one plain store per covered element ----
  #pragma unroll
  for (int i = 0; i < 4; ++i) {
    const int tok = rb * 512 + OFF + R * (j0 + w * 16 + lhi * 4 + i);
    float* dst = Out + ((size_t)tok * NH + h) * DH;
    #pragma unroll
    for (int dt = 0; dt < 4; ++dt)
      dst[dt * 16 + llo] = acc[dt][i];
  }
  // ---- zero-stores for non-dilated phases (replaces memset) ----
  if (R > 1) {
    for (int ri = 0; ri < 16; ++ri) {
      const int tok = rb * 512 + OFF + R * (j0 + w * 16 + ri);
      #pragma unroll
      for (int p = 0; p < R - 1; ++p) {
        const int dz = (R == 2) ? -1 : ((p == 0) ? -2 : ((p == 1) ? -1 : 1));
        Out[((size_t)(tok + dz) * NH + h) * DH + lane] = 0.f;
      }
    }
  }
}

// Grid 896 blocks x 256 threads:
//   A: [0,512)   r=1 heads 0-3, 8 chunks of 64 rows
//   B: [512,768) r=2 heads 4-7, 4 chunks
//   C: [768,896) r=4 heads 8-11, 2 chunks
__global__ __launch_bounds__(256, 4)
void bsda(const float* __restrict__ Q, float* __restrict__ Out,
          const char* __restrict__ Kb, const char* __restrict__ Vt) {
  __shared__ __align__(16) char lds[40960];  // K 16K | V 16K | P 4x2K
  const int bid = blockIdx.x;
  if (bid < 512) {
    const int rb = bid >> 5, rem = bid & 31;
    unit<128, 1>(Q, Out, Kb, Vt, rb, rem >> 3, (rem & 7) * 64, lds);
  } else if (bid < 768) {
    const int b2 = bid - 512, rb = b2 >> 4, rem = b2 & 15;
    unit<128, 2>(Q, Out, Kb, Vt, rb, 4 + (rem >> 2), (rem & 3) * 64, lds);
  } else {
    const int b3 = bid - 768, rb = b3 >> 3, rem = b3 & 7;
    unit<32, 4>(Q, Out, Kb, Vt, rb, 8 + (rem >> 1), (rem & 1) * 64, lds);
  }
}

extern "C" void kernel_launch(void* const* d_in, const int* in_sizes, int n_in,
                              void* d_out, int out_size, void* d_ws, size_t ws_size,
                              hipStream_t stream) {
  const float* q = (const float*)d_in[0];
  const float* k = (const float*)d_in[1];
  const float* v = (const float*)d_in[2];
  float* out = (float*)d_out;

  uint32_t* Kb = (uint32_t*)d_ws;                          // 7,340,032 B
  short*    Vt = (short*)((char*)d_ws + 7340032);          // 7,340,032 B

  prep_k<<<dim3(7168), dim3(256), 0, stream>>>(k, Kb);
  prep_v<<<dim3(896),  dim3(256), 0, stream>>>(v, Vt);
  bsda  <<<dim3(896),  dim3(256), 0, stream>>>(q, out, (const char*)Kb, (const char*)Vt);
}

// Round 10
// 133.378 us; speedup vs baseline: 1.0154x; 1.0154x over previous
//
#include <hip/hip_runtime.h>
#include <stdint.h>

typedef __attribute__((ext_vector_type(8))) short short8;
typedef __attribute__((ext_vector_type(4))) float f32x4;

#define NH 12
#define DH 64

// 2 x f32 -> packed 2 x bf16 (RNE) in one instruction
__device__ __forceinline__ uint32_t cvtpk(float lo, float hi) {
  uint32_t r;
  asm("v_cvt_pk_bf16_f32 %0, %1, %2" : "=v"(r) : "v"(lo), "v"(hi));
  return r;
}

typedef const __attribute__((address_space(1))) uint32_t gu32;
typedef __attribute__((address_space(3))) uint32_t lu32;

__device__ __forceinline__ void gll16(const void* src, void* lds) {
  __builtin_amdgcn_global_load_lds((gu32*)(uintptr_t)src, (lu32*)(uintptr_t)lds, 16, 0, 0);
}

// Per-head base offset in u32 units inside Kb / Vt workspace arrays.
// heads 0-3: r=1 Sd=8192; 4-7: r=2 Sd=4096; 8-11: r=4 Sd=2048; 32 u32/row.
__device__ __forceinline__ int head_base2(int h) {
  return (h < 4) ? (h << 18)
       : (h < 8) ? ((1 << 20) + ((h - 4) << 17))
                 : ((1 << 20) + (1 << 19) + ((h - 8) << 16));
}

// ------------- merged prepass: K gather->bf16, V gather->bf16 transposed ----
// bids [0,7168): K part (1,835,008 u32 pairs). bids [7168,8064): V part.
__global__ __launch_bounds__(256)
void prep(const float* __restrict__ K, const float* __restrict__ V,
          uint32_t* __restrict__ Kb, short* __restrict__ Vt) {
  __shared__ short T[64][72];   // V part only; pad 72 keeps 16B alignment
  const int bid = blockIdx.x, tid = threadIdx.x;
  if (bid < 7168) {
    const int p = bid * 256 + tid;
    int h, r, off, sh, rem;
    if (p < 1048576)      { h = p >> 18;                    rem = p & 262143; r = 1; off = 0; sh = 9; }
    else if (p < 1572864) { int q = p - 1048576; h = 4 + (q >> 17); rem = q & 131071; r = 2; off = 1; sh = 8; }
    else                  { int q = p - 1572864; h = 8 + (q >> 16); rem = q & 65535;  r = 4; off = 2; sh = 7; }
    const int i = rem >> 5, d2 = rem & 31;
    const int j = i & ((1 << sh) - 1), b = i >> sh;
    const int tok = b * 512 + off + r * j;
    const float2 f = *reinterpret_cast<const float2*>(K + ((size_t)tok * NH + h) * DH + d2 * 2);
    Kb[p] = cvtpk(f.x, f.y);
  } else {
    const int vb = bid - 7168;
    int h, r, off, SDB, b, tile;
    if (vb < 512)      { h = vb >> 7;            int rem = vb & 127; b = rem >> 3; tile = rem & 7; r = 1; off = 0; SDB = 512; }
    else if (vb < 768) { int t2 = vb - 512; h = 4 + (t2 >> 6); int rem = t2 & 63; b = rem >> 2; tile = rem & 3; r = 2; off = 1; SDB = 256; }
    else               { int t3 = vb - 768; h = 8 + (t3 >> 5); int rem = t3 & 31; b = rem >> 1; tile = rem & 1; r = 4; off = 2; SDB = 128; }
    const int jj0 = tile * 64;
    const int dl = (tid & 15) * 4, tl0 = tid >> 4;
    #pragma unroll
    for (int rep = 0; rep < 4; ++rep) {
      const int tokl = rep * 16 + tl0;
      const int tok = b * 512 + off + r * (jj0 + tokl);
      const float4 f = *reinterpret_cast<const float4*>(V + ((size_t)tok * NH + h) * DH + dl);
      const uint32_t u01 = cvtpk(f.x, f.y), u23 = cvtpk(f.z, f.w);
      T[dl + 0][tokl] = (short)(u01 & 0xffffu);
      T[dl + 1][tokl] = (short)(u01 >> 16);
      T[dl + 2][tokl] = (short)(u23 & 0xffffu);
      T[dl + 3][tokl] = (short)(u23 >> 16);
    }
    __syncthreads();
    const size_t hbase = (size_t)head_base2(h) * 2;
    #pragma unroll
    for (int cc = 0; cc < 2; ++cc) {
      const int c = tid * 2 + cc, d = c >> 3, s = c & 7;
      short8 v = *reinterpret_cast<const short8*>(&T[d][s * 8]);
      *reinterpret_cast<short8*>(Vt + hbase + (size_t)(b * 64 + d) * SDB + jj0 + s * 8) = v;
    }
  }
}

// ------------------------------ main kernel --------------------------------
// 4-wave block = 64 dilated q-rows of one (rb, h). K/V tiles span the full
// segment (TROWS); staged via global_load_lds from the bf16 prepass arrays
// with pre-swizzled source addresses (linear LDS dest). PV accumulates across
// the <=5 col blocks in registers -> one plain store per output element.
template<int M, int R>
__device__ __forceinline__ void unit(
    const float* __restrict__ Q, float* __restrict__ Out,
    const char* __restrict__ KbB, const char* __restrict__ VtB,
    int rb, int h, int j0, char* lds)
{
  constexpr int OFF    = (R == 1) ? 0 : ((R == 2) ? 1 : 2);
  constexpr int SDB    = 512 / R;
  constexpr int TROWS  = (M == 128) ? 128 : 64;  // K rows / V cols in tile
  constexpr int NT     = M / 16;
  constexpr int HALVES = (M == 128) ? 2 : 1;
  constexpr int TTP    = NT / HALVES;            // tt per half
  constexpr int KKP    = (M == 128) ? 2 : 1;     // PV k-steps per half
  constexpr int PROW   = (M == 128) ? 64 : 32;   // shorts per P row
  constexpr int PMASK  = (M == 128) ? 7 : 3;
  constexpr int VMASK  = (TROWS / 8) - 1;        // 15 or 7
  constexpr int VROWB  = TROWS * 2;              // bytes per V^T row
  constexpr int NSEG   = TROWS / 8;              // 16 or 8 (1KB segs per tile)

  const char* kbh = KbB + (size_t)head_base2(h) * 4;
  const char* vth = VtB + (size_t)head_base2(h) * 4;

  const int tid = threadIdx.x, w = tid >> 6, lane = tid & 63;
  const int lhi = lane >> 4, llo = lane & 15;
  const int jc0  = (M == 128) ? (j0 & ~127) : j0;   // tile/segment col base
  const int c_lo = (M == 128) ? 0 : ((w >> 1) * 32);
  char* Klds = lds;
  char* Vlds = lds + 16384;
  short* const P = (short*)(lds + 32768 + w * 2048);

  // Q fragments, scale log2(e)/8 folded in
  short8 qf0, qf1;
  {
    const float SCL = 0.18033688f;
    const int tok = rb * 512 + OFF + R * (j0 + w * 16 + llo);
    const float* src = Q + ((size_t)tok * NH + h) * DH + lhi * 8;
    float4 a0 = *reinterpret_cast<const float4*>(src);
    float4 a1 = *reinterpret_cast<const float4*>(src + 4);
    float4 b0 = *reinterpret_cast<const float4*>(src + 32);
    float4 b1 = *reinterpret_cast<const float4*>(src + 36);
    union { uint32_t u[4]; short8 s; } x0, x1;
    x0.u[0] = cvtpk(a0.x * SCL, a0.y * SCL); x0.u[1] = cvtpk(a0.z * SCL, a0.w * SCL);
    x0.u[2] = cvtpk(a1.x * SCL, a1.y * SCL); x0.u[3] = cvtpk(a1.z * SCL, a1.w * SCL);
    x1.u[0] = cvtpk(b0.x * SCL, b0.y * SCL); x1.u[1] = cvtpk(b0.z * SCL, b0.w * SCL);
    x1.u[2] = cvtpk(b1.x * SCL, b1.y * SCL); x1.u[3] = cvtpk(b1.z * SCL, b1.w * SCL);
    qf0 = x0.s; qf1 = x1.s;
  }

  f32x4 acc[4];
  #pragma unroll
  for (int dt = 0; dt < 4; ++dt) acc[dt] = f32x4{0.f, 0.f, 0.f, 0.f};

  const int c0 = (rb - 2 < 0) ? 0 : rb - 2;
  const int c1 = (rb + 2 > 15) ? 15 : rb + 2;

  for (int cb = c0; cb <= c1; ++cb) {
    __syncthreads();   // prev iteration's LDS readers done
    // ---- stage K tile: linear LDS dest, inverse-swizzled global src ----
    #pragma unroll
    for (int n = 0; n < NSEG / 4; ++n) {
      const int seg = n * 4 + w;
      const int ck = seg * 64 + lane, t = ck >> 3, sp = ck & 7;
      gll16(kbh + (size_t)(cb * SDB + jc0 + t) * 128 + ((sp ^ (t & 7)) << 4),
            Klds + seg * 1024);
    }
    // ---- stage V^T tile ----
    #pragma unroll
    for (int n = 0; n < NSEG / 4; ++n) {
      const int seg = n * 4 + w;
      const int ck = seg * 64 + lane;
      const int d = ck / (TROWS / 8), sp = ck & VMASK;
      gll16(vth + ((size_t)(cb * 64 + d) * SDB + jc0 + ((sp ^ (d & VMASK)) << 3)) * 2,
            Vlds + seg * 1024);
    }
    __syncthreads();   // drains vmcnt: staged tiles visible

    // ---- QK^T ----
    f32x4 sc[NT];
    #pragma unroll
    for (int tt = 0; tt < NT; ++tt) sc[tt] = f32x4{0.f, 0.f, 0.f, 0.f};
    #pragma unroll
    for (int kk = 0; kk < 2; ++kk) {
      #pragma unroll
      for (int tt = 0; tt < NT; ++tt) {
        const int t = c_lo + tt * 16 + llo;
        const int slot = (4 * kk + lhi) ^ (t & 7);
        short8 kf = *reinterpret_cast<const short8*>(Klds + t * 128 + slot * 16);
        sc[tt] = __builtin_amdgcn_mfma_f32_16x16x32_bf16(kk ? qf1 : qf0, kf, sc[tt], 0, 0, 0);
      }
    }
    // ---- softmax (no max pass: scores bounded, shift-invariant) ----
    float sm[4] = {0.f, 0.f, 0.f, 0.f};
    #pragma unroll
    for (int tt = 0; tt < NT; ++tt)
      #pragma unroll
      for (int i = 0; i < 4; ++i) {
        const float p = exp2f(sc[tt][i]);
        sc[tt][i] = p;
        sm[i] += p;
      }
    #pragma unroll
    for (int i = 0; i < 4; ++i) {
      sm[i] += __shfl_xor(sm[i], 1);
      sm[i] += __shfl_xor(sm[i], 2);
      sm[i] += __shfl_xor(sm[i], 4);
      sm[i] += __shfl_xor(sm[i], 8);
      sm[i] = 1.0f / sm[i];
    }
    // ---- per-half: P -> LDS (2KB/wave buffer), then PV ----
    #pragma unroll
    for (int h2 = 0; h2 < HALVES; ++h2) {
      #pragma unroll
      for (int ttl = 0; ttl < TTP; ++ttl) {
        const int tt = h2 * TTP + ttl;
        #pragma unroll
        for (int ip = 0; ip < 2; ++ip) {
          const uint32_t pk = cvtpk(sc[tt][2 * ip] * sm[2 * ip],
                                    sc[tt][2 * ip + 1] * sm[2 * ip + 1]);
          const int q0 = 4 * lhi + 2 * ip;
          const int chunk = 2 * ttl + (llo >> 3);
          P[q0 * PROW + ((chunk ^ (q0 & PMASK)) << 3) + (llo & 7)] = (short)(pk & 0xffffu);
          P[(q0 + 1) * PROW + ((chunk ^ ((q0 + 1) & PMASK)) << 3) + (llo & 7)] = (short)(pk >> 16);
        }
      }
      #pragma unroll
      for (int kkl = 0; kkl < KKP; ++kkl) {
        const int pch = (KKP == 2) ? (4 * kkl + lhi) : lhi;
        short8 pf = *reinterpret_cast<const short8*>(
            (const short*)P + llo * PROW + ((pch ^ (llo & PMASK)) << 3));
        #pragma unroll
        for (int dt = 0; dt < 4; ++dt) {
          const int d = dt * 16 + llo;
          const int lc = (M == 128) ? (8 * h2 + 4 * kkl + lhi) : (c_lo / 8 + lhi);
          short8 vf = *reinterpret_cast<const short8*>(
              Vlds + d * VROWB + ((lc ^ (d & VMASK)) << 4));
          acc[dt] = __builtin_amdgcn_mfma_f32_16x16x32_bf16(pf, vf, acc[dt], 0, 0, 0);
        }
      }
    }
  }

  // ---- epilogue: one plain store per covered element ----
  #pragma unroll
  for (int i = 0; i < 4; ++i) {
    const int tok = rb * 512 + OFF + R * (j0 + w * 16 + lhi * 4 + i);
    float* dst = Out + ((size_t)tok * NH + h) * DH;
    #pragma unroll
    for (int dt = 0; dt < 4; ++dt)
      dst[dt * 16 + llo] = acc[dt][i];
  }
  // ---- zero-stores for non-dilated phases (replaces memset) ----
  if (R > 1) {
    for (int ri = 0; ri < 16; ++ri) {
      const int tok = rb * 512 + OFF + R * (j0 + w * 16 + ri);
      #pragma unroll
      for (int p = 0; p < R - 1; ++p) {
        const int dz = (R == 2) ? -1 : ((p == 0) ? -2 : ((p == 1) ? -1 : 1));
        Out[((size_t)(tok + dz) * NH + h) * DH + lane] = 0.f;
      }
    }
  }
}

// Grid 896 blocks x 256 threads. XCD-aware bid layout (T1): XCDs get
// consecutive bids round-robin (bid%8). All blocks sharing one (head, jc0)
// tile-group land on ONE XCD so its cb tiles (<=512 KB) stay in that XCD's
// private L2 across the 5 consuming row-blocks.
//   per XCD x: i<32 -> A-group g=x; i<64 -> A-group g=x+8;
//              i<96 -> B-group b=x;  else -> C-group c=x  (112 blocks/XCD)
__global__ __launch_bounds__(256, 4)
void bsda(const float* __restrict__ Q, float* __restrict__ Out,
          const char* __restrict__ Kb, const char* __restrict__ Vt) {
  __shared__ __align__(16) char lds[40960];  // K 16K | V 16K | P 4x2K
  const int x = blockIdx.x & 7;
  const int i = blockIdx.x >> 3;   // 0..111
  if (i < 64) {
    const int g = (i < 32) ? x : (x + 8);   // A-group 0..15: h = g>>2, t4 = g&3
    const int m = i & 31;                   // rb-major within group
    unit<128, 1>(Q, Out, Kb, Vt, m >> 1, g >> 2, (g & 3) * 128 + (m & 1) * 64, lds);
  } else if (i < 96) {
    const int m = i - 64;                   // B-group b=x: h = 4+(x>>1), jc0 = x&1
    unit<128, 2>(Q, Out, Kb, Vt, m >> 1, 4 + (x >> 1), (x & 1) * 128 + (m & 1) * 64, lds);
  } else {
    const int m = i - 96;                   // C-group c=x: h = 8+(x>>1), j0 = (x&1)*64
    unit<32, 4>(Q, Out, Kb, Vt, m, 8 + (x >> 1), (x & 1) * 64, lds);
  }
}

extern "C" void kernel_launch(void* const* d_in, const int* in_sizes, int n_in,
                              void* d_out, int out_size, void* d_ws, size_t ws_size,
                              hipStream_t stream) {
  const float* q = (const float*)d_in[0];
  const float* k = (const float*)d_in[1];
  const float* v = (const float*)d_in[2];
  float* out = (float*)d_out;

  uint32_t* Kb = (uint32_t*)d_ws;                          // 7,340,032 B
  short*    Vt = (short*)((char*)d_ws + 7340032);          // 7,340,032 B

  prep<<<dim3(8064), dim3(256), 0, stream>>>(k, v, Kb, Vt);
  bsda<<<dim3(896),  dim3(256), 0, stream>>>(q, out, (const char*)Kb, (const char*)Vt);
}